// Round 4
// baseline (2782.948 us; speedup 1.0000x reference)
//
#include <hip/hip_runtime.h>
#include <hip/hip_cooperative_groups.h>

namespace cg = cooperative_groups;

namespace {

constexpr int Bn   = 512;   // batch rows
constexpr int INF  = 784;
constexpr int E    = 512;
constexpr int Tn   = 64;    // num blocks
constexpr int ABSZ = 16;    // A * BSZ
constexpr int Jn   = 7;
constexpr int NC   = 128;
constexpr int NT   = 256;   // threads per workgroup
constexpr int DESCMAX = 128;

struct Params {
    const float *x, *emb_W, *emb_b;
    const float *st_W1, *st_b1, *st_W2, *st_b2;
    const float *ad_W1, *ad_b1, *ad_W2, *ad_b2;
    const float *out_W1, *out_b1, *out_W2, *out_b2;
    float *out;
    float *state, *initv, *hbuf, *tbuf, *norms;
    int *idx, *g_rlist;
    int4 *g_desc;
};

// ---------------------------------------------------------------------------
__device__ inline void stage_rows(const float* __restrict__ in, int instride,
                                  int kb, int klen, const int* rid,
                                  float (*s_in)[E], int tid)
{
    #pragma unroll
    for (int g = 0; g < 8; ++g) {
        const float* src = in + (size_t)rid[g] * instride + kb;
        float* dst = s_in[g];
        for (int e4 = tid; e4 < (klen >> 2); e4 += NT)
            reinterpret_cast<float4*>(dst)[e4] =
                reinterpret_cast<const float4*>(src)[e4];
    }
}

__device__ inline void accum8(const float* __restrict__ Wp,
                              const float (*s_in)[E], int klen, float acc[8])
{
    #pragma unroll 2
    for (int e = 0; e < klen; e += 4) {
        const float w0 = Wp[(size_t)(e + 0) * E];
        const float w1 = Wp[(size_t)(e + 1) * E];
        const float w2 = Wp[(size_t)(e + 2) * E];
        const float w3 = Wp[(size_t)(e + 3) * E];
        #pragma unroll
        for (int g = 0; g < 8; ++g) {
            const float4 f = *reinterpret_cast<const float4*>(&s_in[g][e]);
            acc[g] = fmaf(f.x, w0, acc[g]);
            acc[g] = fmaf(f.y, w1, acc[g]);
            acc[g] = fmaf(f.z, w2, acc[g]);
            acc[g] = fmaf(f.w, w3, acc[g]);
        }
    }
}

// build per-WG bucket structures in LDS from global idx; WG0 publishes
__device__ inline int build_buckets(const int* __restrict__ gidx,
                                    int* cnt, int* off, int* rk, int* tb,
                                    int* rlist, int4* sdesc,
                                    int tid, bool pub, const Params& P)
{
    if (tid < Tn) { cnt[tid] = 0; rk[tid] = 0; }
    __syncthreads();
    int rv[2];
    #pragma unroll
    for (int k = 0; k < 2; ++k) rv[k] = gidx[tid + k * NT];
    #pragma unroll
    for (int k = 0; k < 2; ++k) atomicAdd(&cnt[rv[k]], 1);
    __syncthreads();
    if (tid == 0) {
        int s = 0, t = 0;
        for (int b = 0; b < Tn; ++b) {
            off[b] = s; tb[b] = t;
            s += cnt[b]; t += (cnt[b] + 7) >> 3;
        }
        tb[Tn] = t;
    }
    __syncthreads();
    #pragma unroll
    for (int k = 0; k < 2; ++k) {
        const int r = tid + k * NT, b = rv[k];
        rlist[off[b] + atomicAdd(&rk[b], 1)] = r;
    }
    __syncthreads();
    const int nt = tb[Tn];
    for (int t = tid; t < DESCMAX; t += NT) {
        int4 d = make_int4(0, 0, 0, 0);
        if (t < nt) {
            int b = 0;
            while (tb[b + 1] <= t) ++b;
            const int j = t - tb[b];
            d = make_int4(b, off[b] + j * 8, min(8, cnt[b] - j * 8), 0);
        }
        sdesc[t] = d;
    }
    __syncthreads();
    if (pub) {
        for (int r = tid; r < Bn; r += NT) P.g_rlist[r] = rlist[r];
        for (int t = tid; t < DESCMAX; t += NT) P.g_desc[t] = sdesc[t];
    }
    return nt;
}

enum { EPI_EMBED, EPI_H, EPI_T, EPI_FINAL };

// grouped/identity chunked matvec: tiles of <=8 rows x 256-col chunks
template <int EPI>
__device__ void stage_mv(const Params& P, const float* __restrict__ in,
                         int instride, int K,
                         const float* __restrict__ W, const float* __restrict__ bias,
                         bool gathered, int ntiles,
                         const int* __restrict__ rl, const int4* __restrict__ dsc,
                         float* __restrict__ outp,
                         float (*s_in)[E], int tid, int bid, int gridn)
{
    const int items = ntiles * 2;
    for (int s = bid; s < items; s += gridn) {
        const int tile = s >> 1, chunk = s & 1;
        int blk = 0, start = tile * 8, n = 8;
        if (gathered) {
            const int4 d = dsc[tile];
            blk = d.x; start = d.y; n = d.z;
            if (n == 0) continue;
        }
        int rid[8];
        #pragma unroll
        for (int g = 0; g < 8; ++g)
            rid[g] = gathered ? rl[start + min(g, n - 1)] : (start + g);

        float acc[8] = {0, 0, 0, 0, 0, 0, 0, 0};
        for (int kb = 0; kb < K; kb += E) {
            const int klen = min(E, K - kb);
            __syncthreads();
            stage_rows(in, instride, kb, klen, rid, s_in, tid);
            __syncthreads();
            const float* Wp = W + (size_t)blk * K * E + (size_t)kb * E
                              + (chunk * NT + tid);
            accum8(Wp, s_in, klen, acc);
        }
        const int c = chunk * NT + tid;
        const float bv = bias[(gathered ? blk * E : 0) + c];
        #pragma unroll
        for (int g = 0; g < 8; ++g) {
            if (g < n) {
                float v = acc[g] + bv;
                const size_t o = (size_t)rid[g] * E + c;
                if (EPI == EPI_EMBED) {
                    P.state[o] = v; P.initv[o] = v;
                } else if (EPI == EPI_H) {
                    outp[o] = fmaxf(v, 0.f);
                } else if (EPI == EPI_T) {
                    outp[o] = fmaxf(v, 0.f) / (P.norms[rid[g]] + 1e-6f);
                } else {  // EPI_FINAL
                    P.state[o] = fmaxf(v, 0.f) / (P.norms[rid[g]] + 1e-6f)
                                 + P.initv[o];
                }
            }
        }
    }
}

// address stage: full-width mv ad_W1 + logits(ad_W2) + argmax -> idx,
// plus optional state update (state = t + ramp*init) and norm of new state
template <bool UPDATE>
__device__ void stage_addr(const Params& P, const float* __restrict__ in,
                           float ramp, bool gathered, int ntiles,
                           const int* __restrict__ rl, const int4* __restrict__ dsc,
                           float (*s_in)[E], float* slog,
                           int tid, int bid, int gridn)
{
    for (int s = bid; s < ntiles; s += gridn) {
        int blk = 0, start = s * 8, n = 8;
        if (gathered) {
            const int4 d = dsc[s];
            blk = d.x; start = d.y; n = d.z;
            if (n == 0) continue;
        }
        int rid[8];
        #pragma unroll
        for (int g = 0; g < 8; ++g)
            rid[g] = gathered ? rl[start + min(g, n - 1)] : (start + g);

        __syncthreads();
        stage_rows(in, E, 0, E, rid, s_in, tid);
        __syncthreads();

        const float* W1 = P.ad_W1 + (size_t)blk * E * E;
        float a0[8] = {0, 0, 0, 0, 0, 0, 0, 0};
        float a1[8] = {0, 0, 0, 0, 0, 0, 0, 0};
        #pragma unroll 2
        for (int e = 0; e < E; e += 4) {
            float w0[4], w1v[4];
            #pragma unroll
            for (int q = 0; q < 4; ++q) {
                w0[q]  = W1[(size_t)(e + q) * E + tid];
                w1v[q] = W1[(size_t)(e + q) * E + tid + NT];
            }
            #pragma unroll
            for (int g = 0; g < 8; ++g) {
                const float4 f = *reinterpret_cast<const float4*>(&s_in[g][e]);
                a0[g] = fmaf(f.x, w0[0], a0[g]);
                a0[g] = fmaf(f.y, w0[1], a0[g]);
                a0[g] = fmaf(f.z, w0[2], a0[g]);
                a0[g] = fmaf(f.w, w0[3], a0[g]);
                a1[g] = fmaf(f.x, w1v[0], a1[g]);
                a1[g] = fmaf(f.y, w1v[1], a1[g]);
                a1[g] = fmaf(f.z, w1v[2], a1[g]);
                a1[g] = fmaf(f.w, w1v[3], a1[g]);
            }
        }

        // state update + per-row norm (32 threads per row, from staged input)
        {
            const int g = tid >> 5, l = tid & 31;
            if (g < n) {
                const int r = rid[g];
                float ss = 0.f;
                const int e0 = l * 16;
                #pragma unroll
                for (int e = e0; e < e0 + 16; e += 4) {
                    float4 tv = *reinterpret_cast<const float4*>(&s_in[g][e]);
                    if (UPDATE) {
                        const float4 iv = *reinterpret_cast<const float4*>(
                            &P.initv[(size_t)r * E + e]);
                        tv.x = fmaf(ramp, iv.x, tv.x);
                        tv.y = fmaf(ramp, iv.y, tv.y);
                        tv.z = fmaf(ramp, iv.z, tv.z);
                        tv.w = fmaf(ramp, iv.w, tv.w);
                        *reinterpret_cast<float4*>(&P.state[(size_t)r * E + e]) = tv;
                    }
                    ss += tv.x * tv.x + tv.y * tv.y + tv.z * tv.z + tv.w * tv.w;
                }
                #pragma unroll
                for (int m = 16; m > 0; m >>= 1) ss += __shfl_xor(ss, m, 64);
                if (l == 0) P.norms[r] = sqrtf(ss);
            }
        }
        __syncthreads();   // done reading s_in; safe to overwrite with h_ad

        const float bb0 = P.ad_b1[blk * E + tid];
        const float bb1 = P.ad_b1[blk * E + tid + NT];
        #pragma unroll
        for (int g = 0; g < 8; ++g) {
            s_in[g][tid]      = fmaxf(a0[g] + bb0, 0.f);
            s_in[g][tid + NT] = fmaxf(a1[g] + bb1, 0.f);
        }
        __syncthreads();

        // logits: 128 dots (8 rows x 16 outputs), 2 threads per dot
        {
            const int d = tid >> 1, half = tid & 1;
            const int row = d >> 4, o = d & 15;
            const float* W2 = P.ad_W2 + (size_t)blk * E * ABSZ;
            float lacc = 0.f;
            const int e0 = half * 256;
            #pragma unroll 4
            for (int e = e0; e < e0 + 256; ++e)
                lacc = fmaf(s_in[row][e], W2[(size_t)e * ABSZ + o], lacc);
            lacc += __shfl_xor(lacc, 1, 64);
            if (half == 0) slog[d] = lacc + P.ad_b2[blk * ABSZ + o];
        }
        __syncthreads();
        if (tid < n) {
            const float* L = slog + tid * ABSZ;
            int A0 = 0, A1 = 0;
            float m0 = L[0], m1 = L[8];
            #pragma unroll
            for (int k = 1; k < 8; ++k) {
                if (L[k]     > m0) { m0 = L[k];     A0 = k; }
                if (L[8 + k] > m1) { m1 = L[8 + k]; A1 = k; }
            }
            P.idx[rid[tid]] = A0 * 8 + A1;
        }
        __syncthreads();
    }
}

// ---------------------------------------------------------------------------
__global__ __launch_bounds__(NT, 2) void brain_fused(Params P)
{
    cg::grid_group grid = cg::this_grid();
    const int tid = threadIdx.x, bid = blockIdx.x, gridn = gridDim.x;

    __shared__ float s_in[8][E];          // 16 KB staging / h_ad buffer
    __shared__ int   rlist[Bn];           // 2 KB
    __shared__ int4  sdesc[DESCMAX];      // 2 KB
    __shared__ int   cnt[Tn], off[Tn], rk[Tn], tb[Tn + 1];
    __shared__ float slog[8 * ABSZ];

    // --- embed: state = init = x @ emb_W + emb_b
    stage_mv<EPI_EMBED>(P, P.x, INF, INF, P.emb_W, P.emb_b,
                        false, Bn / 8, nullptr, nullptr, nullptr,
                        s_in, tid, bid, gridn);
    grid.sync();

    // --- initial address from block 0 on initial_state (also computes norms)
    stage_addr<false>(P, P.initv, 0.f, false, Bn / 8, nullptr, nullptr,
                      s_in, slog, tid, bid, gridn);
    grid.sync();

    // --- jump loop
    for (int i = 0; i < Jn; ++i) {
        const int nt = build_buckets(P.idx, cnt, off, rk, tb, rlist, sdesc,
                                     tid, bid == 0, P);
        stage_mv<EPI_H>(P, P.state, E, E, P.st_W1, P.st_b1,
                        true, nt, rlist, sdesc, P.hbuf,
                        s_in, tid, bid, gridn);
        grid.sync();
        stage_mv<EPI_T>(P, P.hbuf, E, E, P.st_W2, P.st_b2,
                        true, nt, P.g_rlist, P.g_desc, P.tbuf,
                        s_in, tid, bid, gridn);
        grid.sync();
        stage_addr<true>(P, P.tbuf, (float)i * (1.0f / 6.0f),
                         true, nt, P.g_rlist, P.g_desc,
                         s_in, slog, tid, bid, gridn);
        grid.sync();
    }

    // --- final through_block + init
    {
        const int nt = build_buckets(P.idx, cnt, off, rk, tb, rlist, sdesc,
                                     tid, bid == 0, P);
        stage_mv<EPI_H>(P, P.state, E, E, P.st_W1, P.st_b1,
                        true, nt, rlist, sdesc, P.hbuf,
                        s_in, tid, bid, gridn);
        grid.sync();
        stage_mv<EPI_FINAL>(P, P.hbuf, E, E, P.st_W2, P.st_b2,
                            true, nt, P.g_rlist, P.g_desc, nullptr,
                            s_in, tid, bid, gridn);
        grid.sync();
    }

    // --- output head: h = relu(final @ out_W1 + out_b1)
    stage_mv<EPI_H>(P, P.state, E, E, P.out_W1, P.out_b1,
                    false, Bn / 8, nullptr, nullptr, P.hbuf,
                    s_in, tid, bid, gridn);
    grid.sync();

    // --- out = h @ out_W2 + out_b2
    for (int s = bid; s < Bn / 8; s += gridn) {
        const int base = s * 8;
        int rid[8];
        #pragma unroll
        for (int g = 0; g < 8; ++g) rid[g] = base + g;
        __syncthreads();
        stage_rows(P.hbuf, E, 0, E, rid, s_in, tid);
        __syncthreads();
        const int col = tid & (NC - 1), rg = tid >> 7;
        float acc[4] = {0, 0, 0, 0};
        #pragma unroll 4
        for (int e = 0; e < E; e += 2) {
            const float w0 = P.out_W2[(size_t)e * NC + col];
            const float w1 = P.out_W2[(size_t)(e + 1) * NC + col];
            #pragma unroll
            for (int j = 0; j < 4; ++j) {
                const int g = rg * 4 + j;
                acc[j] = fmaf(s_in[g][e], w0, acc[j]);
                acc[j] = fmaf(s_in[g][e + 1], w1, acc[j]);
            }
        }
        const float bv = P.out_b2[col];
        #pragma unroll
        for (int j = 0; j < 4; ++j)
            P.out[(size_t)(base + rg * 4 + j) * NC + col] = acc[j] + bv;
    }
}

}  // namespace

extern "C" void kernel_launch(void* const* d_in, const int* in_sizes, int n_in,
                              void* d_out, int out_size, void* d_ws, size_t ws_size,
                              hipStream_t stream)
{
    Params p;
    p.x      = (const float*)d_in[0];
    p.emb_W  = (const float*)d_in[1];
    p.emb_b  = (const float*)d_in[2];
    p.st_W1  = (const float*)d_in[3];
    p.st_b1  = (const float*)d_in[4];
    p.st_W2  = (const float*)d_in[5];
    p.st_b2  = (const float*)d_in[6];
    p.ad_W1  = (const float*)d_in[7];
    p.ad_b1  = (const float*)d_in[8];
    p.ad_W2  = (const float*)d_in[9];
    p.ad_b2  = (const float*)d_in[10];
    p.out_W1 = (const float*)d_in[11];
    p.out_b1 = (const float*)d_in[12];
    p.out_W2 = (const float*)d_in[13];
    p.out_b2 = (const float*)d_in[14];
    p.out    = (float*)d_out;

    float* ws = (float*)d_ws;
    p.state = ws;
    p.initv = ws + 1 * 262144;
    p.hbuf  = ws + 2 * 262144;
    p.tbuf  = ws + 3 * 262144;
    p.norms = ws + 4 * 262144;
    p.idx     = (int*)(p.norms + Bn);
    p.g_rlist = p.idx + Bn;
    p.g_desc  = (int4*)(p.g_rlist + Bn);

    int occ = 0;
    hipOccupancyMaxActiveBlocksPerMultiprocessor(&occ, brain_fused, NT, 0);
    if (occ < 1) occ = 1;
    int grid = occ * 256;           // 256 CUs on MI355X
    if (grid > 512) grid = 512;

    void* args[] = { &p };
    hipLaunchCooperativeKernel((const void*)brain_fused, dim3(grid), dim3(NT),
                               args, 0, stream);
}